// Round 1
// baseline (217.741 us; speedup 1.0000x reference)
//
#include <hip/hip_runtime.h>
#include <stdint.h>

#define NCOMP 8
#define LATD  512
#define HID   1024
#define OUTD  512
#define NS    16384

typedef unsigned short u16;
typedef __bf16 bf16x8 __attribute__((ext_vector_type(8)));
typedef float  f32x4  __attribute__((ext_vector_type(4)));

// ---- workspace layout (bytes) ----
// ctrl block: counts[8] @0, cursors[8] @32, offsets[9] @64, sigma[8] @128
#define ORDER_OFF  256
#define APACK_OFF  (ORDER_OFF + NS*4)                               // 65792 (16B aligned)
#define W1T_OFF    (APACK_OFF + (size_t)NS*LATD*2)                  // +16.8MB
#define W2T_OFF    (W1T_OFF + (size_t)NCOMP*LATD*HID*2)             // +8.4MB
#define H_OFF      (W2T_OFF + (size_t)NCOMP*HID*OUTD*2)             // +8.4MB
#define WS_NEEDED  (H_OFF + (size_t)NS*HID*2)                       // total ~64.1MB

__device__ __forceinline__ u16 f2b(float f) {         // fp32 -> bf16 RNE
  unsigned int u = __builtin_bit_cast(unsigned int, f);
  u = (u + 0x7FFFu + ((u >> 16) & 1u)) >> 16;
  return (u16)u;
}

__device__ __forceinline__ void load_lds16(const void* g, void* l) {
  // global->LDS DMA, 16B/lane; LDS dest = wave-uniform base + lane*16
  __builtin_amdgcn_global_load_lds((const __attribute__((address_space(1))) void*)g,
                                   (__attribute__((address_space(3))) void*)l, 16, 0, 0);
}

// ---------------- bucketing ----------------
__global__ void k_count(const int* __restrict__ idx, int* __restrict__ counts) {
  __shared__ int h[NCOMP];
  int t = threadIdx.x;
  if (t < NCOMP) h[t] = 0;
  __syncthreads();
  int n = blockIdx.x*256 + t;
  if (n < NS) atomicAdd(&h[idx[n]], 1);
  __syncthreads();
  if (t < NCOMP) atomicAdd(&counts[t], h[t]);
}

__global__ void k_scan(const int* __restrict__ counts, int* __restrict__ offsets,
                       const float* __restrict__ rho, float* __restrict__ sigma) {
  if (threadIdx.x == 0) {
    int acc = 0;
    for (int c = 0; c < NCOMP; ++c) { offsets[c] = acc; acc += counts[c]; }
    offsets[NCOMP] = acc;
  }
  if (threadIdx.x < NCOMP) {
    float r = rho[threadIdx.x];
    sigma[threadIdx.x] = (r > 20.f) ? r : log1pf(expf(r));   // softplus
  }
}

__global__ void k_scatter(const int* __restrict__ idx, const int* __restrict__ offsets,
                          int* __restrict__ cursors, int* __restrict__ order) {
  __shared__ int lh[NCOMP];
  __shared__ int lbase[NCOMP];
  int t = threadIdx.x;
  if (t < NCOMP) lh[t] = 0;
  __syncthreads();
  int n = blockIdx.x*256 + t;
  int c = 0, rank = 0;
  if (n < NS) { c = idx[n]; rank = atomicAdd(&lh[c], 1); }
  __syncthreads();
  if (t < NCOMP) lbase[t] = atomicAdd(&cursors[t], lh[t]);
  __syncthreads();
  if (n < NS) order[offsets[c] + lbase[c] + rank] = n;
}

// ---------------- pack A: lat = eps*sigma_c + mu_c, bucket-ordered, bf16 ----------------
__global__ void k_pack(const float* __restrict__ eps, const int* __restrict__ idx,
                       const float* __restrict__ mu, const float* __restrict__ sigma,
                       const int* __restrict__ order, u16* __restrict__ Apack) {
  int g = blockIdx.x*256 + threadIdx.x;   // NS*64 threads, 8 elems each
  int i = g >> 6;
  int d = (g & 63) << 3;
  if (i >= NS) return;
  int s = order[i];
  int c = idx[s];
  float sg = sigma[c];
  const float4* ep = reinterpret_cast<const float4*>(eps + (size_t)s*LATD + d);
  const float4* mp = reinterpret_cast<const float4*>(mu  + (size_t)c*LATD + d);
  float4 e0 = ep[0], e1 = ep[1], m0 = mp[0], m1 = mp[1];
  unsigned o0 = f2b(e0.x*sg+m0.x), o1 = f2b(e0.y*sg+m0.y), o2 = f2b(e0.z*sg+m0.z), o3 = f2b(e0.w*sg+m0.w);
  unsigned o4 = f2b(e1.x*sg+m1.x), o5 = f2b(e1.y*sg+m1.y), o6 = f2b(e1.z*sg+m1.z), o7 = f2b(e1.w*sg+m1.w);
  uint4 pk;
  pk.x = o0 | (o1<<16); pk.y = o2 | (o3<<16); pk.z = o4 | (o5<<16); pk.w = o6 | (o7<<16);
  *reinterpret_cast<uint4*>(Apack + (size_t)i*LATD + d) = pk;
}

// ---------------- transpose + fp32->bf16: in [C][R][CC] -> out [C][CC][R] ----------------
template<int R, int CC>
__global__ void k_transpose(const float* __restrict__ W, u16* __restrict__ WT) {
  __shared__ float tile[64][65];
  int c  = blockIdx.z;
  int r0 = blockIdx.y*64, c0 = blockIdx.x*64;
  const float* src = W  + (size_t)c*R*CC;
  u16*        dst  = WT + (size_t)c*R*CC;
  int tx = threadIdx.x & 63, ty = threadIdx.x >> 6;
  for (int rr = ty; rr < 64; rr += 4)
    tile[rr][tx] = src[(size_t)(r0+rr)*CC + c0 + tx];
  __syncthreads();
  for (int rr = ty; rr < 64; rr += 4)
    dst[(size_t)(c0+rr)*R + r0 + tx] = f2b(tile[tx][rr]);
}

// ---------------- m97-structure bf16 GEMM, per-component tiles ----------------
// A: [*][K] bf16 packed rows.  BT: [C][NB][K] bf16 (B^T).  128x128 tile, 4 waves,
// 4x4 16x16x32 MFMA frags/wave, BK=64, global_load_lds width=16.
// STAGE 1: +b1, sigmoid, bf16 store to Hout.  STAGE 2: +b2, fp32 scatter-store via order.
template<int K, int NB, int STAGE>
__global__ __launch_bounds__(256, 2)
void k_gemm(const u16* __restrict__ A, const u16* __restrict__ BT,
            const int* __restrict__ offsets, const int* __restrict__ order,
            const float* __restrict__ bias,
            u16* __restrict__ Hout, float* __restrict__ Yout) {
  __shared__ u16 As[128*64];
  __shared__ u16 Bs[128*64];
  __shared__ int ord[128];

  const int c = blockIdx.z;
  const int bstart = offsets[c];
  const int bend   = offsets[c+1];
  const int tile0  = bstart + blockIdx.y*128;
  if (tile0 >= bend) return;                 // empty tile slot (uniform exit)
  const int ncol0 = blockIdx.x*128;

  const int tid  = threadIdx.x;
  const int wave = tid >> 6;
  const int lane = tid & 63;
  const int srow = (wave<<5) + (lane>>3);    // staging row within tile
  const int scol = (lane&7)<<3;              // staging k-element offset

  if (STAGE == 2 && tid < 128) {
    int gr = tile0 + tid;
    ord[tid] = order[gr < bend ? gr : bstart];
  }

  size_t a_off[4], b_off[4];
  const size_t bbase = (size_t)c * NB * K;
  #pragma unroll
  for (int i = 0; i < 4; ++i) {
    int ar = tile0 + srow + (i<<3);
    if (ar >= bend) ar = bend - 1;           // clamp reads inside bucket (stores guarded)
    a_off[i] = (size_t)ar * K + scol;
    b_off[i] = bbase + (size_t)(ncol0 + srow + (i<<3)) * K + scol;
  }

  const int wr   = (wave >> 1) << 6;
  const int wc   = (wave & 1) << 6;
  const int quad = lane >> 4;
  const int l16  = lane & 15;

  float bcol[4];
  #pragma unroll
  for (int ni = 0; ni < 4; ++ni)
    bcol[ni] = bias[(size_t)c*NB + ncol0 + wc + (ni<<4) + l16];

  f32x4 acc[4][4] = {};

  for (int k0 = 0; k0 < K; k0 += 64) {
    #pragma unroll
    for (int i = 0; i < 4; ++i)
      load_lds16(A + a_off[i] + k0, &As[((wave<<5) + (i<<3))<<6]);
    #pragma unroll
    for (int i = 0; i < 4; ++i)
      load_lds16(BT + b_off[i] + k0, &Bs[((wave<<5) + (i<<3))<<6]);
    __syncthreads();
    #pragma unroll
    for (int kk = 0; kk < 64; kk += 32) {
      bf16x8 af[4], bfr[4];
      #pragma unroll
      for (int mi = 0; mi < 4; ++mi)
        af[mi] = *reinterpret_cast<const bf16x8*>(&As[((wr + (mi<<4) + l16)<<6) + kk + (quad<<3)]);
      #pragma unroll
      for (int ni = 0; ni < 4; ++ni)
        bfr[ni] = *reinterpret_cast<const bf16x8*>(&Bs[((wc + (ni<<4) + l16)<<6) + kk + (quad<<3)]);
      #pragma unroll
      for (int mi = 0; mi < 4; ++mi)
        #pragma unroll
        for (int ni = 0; ni < 4; ++ni)
          acc[mi][ni] = __builtin_amdgcn_mfma_f32_16x16x32_bf16(af[mi], bfr[ni], acc[mi][ni], 0, 0, 0);
    }
    __syncthreads();
  }

  // epilogue: C/D layout col=lane&15, row=quad*4+reg
  #pragma unroll
  for (int mi = 0; mi < 4; ++mi) {
    #pragma unroll
    for (int r = 0; r < 4; ++r) {
      const int row_l = wr + (mi<<4) + (quad<<2) + r;
      const int grow  = tile0 + row_l;
      if (grow < bend) {
        #pragma unroll
        for (int ni = 0; ni < 4; ++ni) {
          const int col = ncol0 + wc + (ni<<4) + l16;
          float v = acc[mi][ni][r] + bcol[ni];
          if (STAGE == 1) {
            v = 1.0f / (1.0f + __expf(-v));
            Hout[(size_t)grow*NB + col] = f2b(v);
          } else {
            Yout[(size_t)ord[row_l]*NB + col] = v;
          }
        }
      }
    }
  }
}

// ---------------- fallback (ws too small): naive per-sample MLP ----------------
__global__ void k_naive(const float* __restrict__ eps, const int* __restrict__ idx,
                        const float* __restrict__ mu, const float* __restrict__ rho,
                        const float* __restrict__ W1, const float* __restrict__ b1,
                        const float* __restrict__ W2, const float* __restrict__ b2,
                        float* __restrict__ out) {
  __shared__ float lat[LATD];
  __shared__ float h[HID];
  int n = blockIdx.x, t = threadIdx.x;
  int c = idx[n];
  float r = rho[c];
  float sg = (r > 20.f) ? r : log1pf(expf(r));
  for (int d = t; d < LATD; d += 256) lat[d] = eps[(size_t)n*LATD+d]*sg + mu[(size_t)c*LATD+d];
  __syncthreads();
  for (int j = t; j < HID; j += 256) {
    float a = b1[(size_t)c*HID+j];
    const float* w = W1 + (size_t)c*LATD*HID + j;
    for (int d = 0; d < LATD; ++d) a += lat[d]*w[(size_t)d*HID];
    h[j] = 1.f/(1.f+expf(-a));
  }
  __syncthreads();
  for (int o = t; o < OUTD; o += 256) {
    float a = b2[(size_t)c*OUTD+o];
    const float* w = W2 + (size_t)c*HID*OUTD + o;
    for (int j = 0; j < HID; ++j) a += h[j]*w[(size_t)j*OUTD];
    out[(size_t)n*OUTD+o] = a;
  }
}

extern "C" void kernel_launch(void* const* d_in, const int* in_sizes, int n_in,
                              void* d_out, int out_size, void* d_ws, size_t ws_size,
                              hipStream_t stream) {
  const float* eps = (const float*)d_in[0];
  const int*   idx = (const int*)d_in[1];
  const float* mu  = (const float*)d_in[2];
  const float* rho = (const float*)d_in[3];
  const float* W1  = (const float*)d_in[4];
  const float* b1  = (const float*)d_in[5];
  const float* W2  = (const float*)d_in[6];
  const float* b2  = (const float*)d_in[7];
  float* out = (float*)d_out;

  if (ws_size < WS_NEEDED) {     // insurance only
    k_naive<<<NS, 256, 0, stream>>>(eps, idx, mu, rho, W1, b1, W2, b2, out);
    return;
  }

  char* ws = (char*)d_ws;
  int*   counts  = (int*)(ws + 0);
  int*   cursors = (int*)(ws + 32);
  int*   offsets = (int*)(ws + 64);
  float* sigma   = (float*)(ws + 128);
  int*   order   = (int*)(ws + ORDER_OFF);
  u16*   Apack   = (u16*)(ws + APACK_OFF);
  u16*   W1T     = (u16*)(ws + W1T_OFF);
  u16*   W2T     = (u16*)(ws + W2T_OFF);
  u16*   Hws     = (u16*)(ws + H_OFF);

  hipMemsetAsync(ws, 0, 256, stream);
  k_count  <<<64, 256, 0, stream>>>(idx, counts);
  k_scan   <<<1, 64, 0, stream>>>(counts, offsets, rho, sigma);
  k_scatter<<<64, 256, 0, stream>>>(idx, offsets, cursors, order);
  k_pack   <<<NS*64/256, 256, 0, stream>>>(eps, idx, mu, sigma, order, Apack);
  k_transpose<LATD, HID><<<dim3(HID/64, LATD/64, NCOMP), 256, 0, stream>>>(W1, W1T);
  k_transpose<HID, OUTD><<<dim3(OUTD/64, HID/64, NCOMP), 256, 0, stream>>>(W2, W2T);
  // GEMM1: [Nc x 512] @ [512 x 1024] -> sigmoid -> H (bf16)
  k_gemm<LATD, HID, 1><<<dim3(HID/128, NS/128, NCOMP), 256, 0, stream>>>(
      Apack, W1T, offsets, order, b1, Hws, nullptr);
  // GEMM2: [Nc x 1024] @ [1024 x 512] -> +b2 -> scatter fp32 out
  k_gemm<HID, OUTD, 2><<<dim3(OUTD/128, NS/128, NCOMP), 256, 0, stream>>>(
      Hws, W2T, offsets, order, b2, nullptr, out);
}